// Round 9
// baseline (482.960 us; speedup 1.0000x reference)
//
#include <hip/hip_runtime.h>

// LSTM (B=2048, T=1024, I=8, H=64) + sigmoid(FC), bf16 MFMA, in-register
// activations, duplicate-column split, 2 blocks/CU — ANTI-PHASE + PIPELINED
// X-PROJECTION revision.
//
// r8 (393us, WIN): one-time ~384cy s_sleep stagger for half the blocks seeds
// MFMA/VALU anti-phase between the 2 co-resident blocks (verified:
// MfmaUtil 48 + VALUBusy 64.5 = 112.5% > 100%). DO NOT REMOVE THE STAGGER.
//
// r9 (this revision): shrink the post-barrier serial head (~270cy of the
// 923cy wall above the ~650cy anti-phase floor). The x-projection MFMAs for
// step t+1 are seeded MID-STEP t into accX[4] (x_lds[xb][tt+1] is stable all
// chunk), executing during act/barrier. Post-barrier chain drops from
// {3 ds_read -> 3-deep MFMA} to {2 ds_read -> 2-deep MFMA}:
//   acc = a2*fh1 + (a1*fh0 + accX).
// Chunk-boundary step (tt==0) seeds in-step (3-deep, 1/32 steps,
// compile-time branch under the full unroll). This is the r1/r5 idea minus
// their confounders: no asm barriers, no partial unroll, no split select
// tree — gsel/act/stagger byte-identical to r8.
//
// Verified keeps: HP=80 (r0's 40 aliased h rows — correctness), __expf
// (r2: exp2f lowers to slow ocml), v_cvt_pk_bf16_f32 h-store, plain
// __syncthreads, full unroll on tt.

namespace {
constexpr int T_LEN = 1024;
constexpr int R     = 4;    // batch rows per block
constexpr int TS    = 32;   // timesteps of x per staged chunk
constexpr int HP    = 80;   // h_lds row stride in shorts (160 B, 16B-aligned)

typedef __attribute__((ext_vector_type(8))) short  short8v;
typedef __attribute__((ext_vector_type(4))) float  float4v;
typedef unsigned short u16;
typedef unsigned long long u64;
typedef unsigned int u32;

__device__ __forceinline__ float fsig(float x) {
  return __builtin_amdgcn_rcpf(1.f + __expf(-x));
}
__device__ __forceinline__ float ftanh(float x) {
  return 1.f - 2.f * __builtin_amdgcn_rcpf(__expf(2.f * x) + 1.f);
}
__device__ __forceinline__ u16 f2bf(float f) {  // RNE (init-time only)
  u32 u = __float_as_uint(f);
  u32 r = ((u >> 16) & 1u) + 0x7fffu;
  return (u16)((u + r) >> 16);
}
__device__ __forceinline__ u16 cvt_bf16(float f) {  // 1 VALU op, RNE
  u32 d;
  asm("v_cvt_pk_bf16_f32 %0, %1, %2" : "=v"(d) : "v"(f), "v"(f));
  return (u16)d;
}

__global__ __launch_bounds__(256, 2) void lstm_split(
    const float* __restrict__ x,     // [B, T, 8]
    const float* __restrict__ W_ih,  // [256, 8]
    const float* __restrict__ W_hh,  // [256, 64]
    const float* __restrict__ b_ih,  // [256]
    const float* __restrict__ b_hh,  // [256]
    const float* __restrict__ fc_w,  // [64]
    const float* __restrict__ fc_b,  // [1]
    float* __restrict__ out) {       // [B]
  __shared__ __align__(16) u16   x_lds[2][TS][R][32];  // 16 KB; full K-rows
  __shared__ __align__(16) u16   h_lds[2][R][HP];      // 2.5 KB
  __shared__ __align__(16) float hf[R][64];            // final h (fp32)

  const int tid  = threadIdx.x;
  const int lane = tid & 63;
  const int wv   = tid >> 6;       // wave 0..3
  const int g4   = lane >> 4;      // MFMA k-quad / C row-quad
  const int nib  = lane & 15;      // MFMA m/n coord
  const int row  = nib & 3;        // batch row (cols 4..15 duplicate 0..3)
  const int rsel = nib >> 2;       // which acc reg this thread activates
  const int jh   = 16 * wv + 4 * g4 + rsel;  // owned h index
  const int bBase = blockIdx.x * R;

  // ---- static A fragments: wave wv holds tiles {4g+wv}, g=0..3 (i,f,g,o) ----
  // A[m=16*(4g+wv)+nib][k=8*g4+j]; frag0 k=0..31 = [W_ih(8)|bias|0...],
  // frag1 = W_hh[:,0:32], frag2 = W_hh[:,32:64].
  short8v a0[4], a1[4], a2[4];
  for (int g = 0; g < 4; ++g) {
    const int n = 64 * g + 16 * wv + nib;  // gate row
    short8v f0, f1, f2;
    for (int j = 0; j < 8; ++j) {
      const int k = 8 * g4 + j;
      float v0 = 0.f;
      if (k < 8) v0 = W_ih[n * 8 + k];
      else if (k == 8) v0 = b_ih[n] + b_hh[n];
      f0[j] = (short)f2bf(v0);
      f1[j] = (short)f2bf(W_hh[n * 64 + k]);
      f2[j] = (short)f2bf(W_hh[n * 64 + 32 + k]);
    }
    a0[g] = f0; a1[g] = f1; a2[g] = f2;
  }

  // ---- LDS init: h0 = 0 (both bufs); x constant channels once per buf ----
  for (int i = tid; i < 2 * R * HP; i += 256) ((u16*)h_lds)[i] = 0;
  {  // 256 threads <-> 2 bufs x 32 tt x 4 rows
    const int buf = tid >> 7, rem = tid & 127, tt = rem >> 2, rr = rem & 3;
    u16* p = &x_lds[buf][tt][rr][0];
    p[8] = 0x3f80;  // bias channel = 1.0
    for (int chn = 9; chn < 32; ++chn) p[chn] = 0;
  }

  // ---- x staging: 1 float4/thread/chunk, double-buffered ----
  float4v xr;
  const int sr = tid >> 6, sm = tid & 63;          // src row, float4 idx
  const int stt = sm >> 1, sch = (sm & 1) * 4;     // dest tt, channel
  auto stage_load = [&](int chunk) {
    const float* src = x + ((size_t)bBase + sr) * (T_LEN * 8) +
                       (size_t)chunk * (TS * 8);
    xr = *(const float4v*)&src[sm * 4];
  };
  auto stage_write = [&](int buf) {
    u32 lo, hi;
    asm("v_cvt_pk_bf16_f32 %0, %1, %2" : "=v"(lo) : "v"(xr[0]), "v"(xr[1]));
    asm("v_cvt_pk_bf16_f32 %0, %1, %2" : "=v"(hi) : "v"(xr[2]), "v"(xr[3]));
    const u64 p = ((u64)hi << 32) | (u64)lo;
    *(u64*)&x_lds[buf][stt][sr][sch] = p;
  };

  stage_load(0);
  stage_write(0);
  __syncthreads();

  // ---- ANTI-PHASE SEED: one-time ~384cy stagger for half the blocks ----
  // Splits co-resident pairs whether the CU pairing is (i, i+256) (XCD
  // round-robin, differs in bit 8) or (2i, 2i+1) (differs in bit 0).
  if (((blockIdx.x ^ (blockIdx.x >> 8)) & 1) != 0)
    __builtin_amdgcn_s_sleep(6);  // 6*64 = 384 cycles, once

  // hoisted select masks for the cndmask tree
  const bool sel1 = (rsel & 1) != 0;
  const bool sel2 = (rsel & 2) != 0;
  float c = 0.f;

  float4v accX[4];  // x-projection pipeline register (seeded one step ahead)

  for (int ch = 0; ch < T_LEN / TS; ++ch) {
    const int xb = ch & 1;
    const bool more = (ch < T_LEN / TS - 1);
#pragma unroll
    for (int tt = 0; tt < TS; ++tt) {
      const int t = ch * TS + tt;
      const int hb = t & 1;  // == tt & 1 (TS even); compile-time under unroll
      if (tt == 0 && more) stage_load(ch + 1);  // reg loads; drain in stage_write

      // ---- post-barrier head: h fragments (2 uniform b128 reads) ----
      const short8v fh0 = *(const short8v*)&h_lds[hb][row][8 * g4];
      const short8v fh1 = *(const short8v*)&h_lds[hb][row][32 + 8 * g4];

      // chunk-boundary: accX not seeded (x buffer was restaged) -> in-step
      if (tt == 0) {
        const short8v fx0 = *(const short8v*)&x_lds[xb][0][row][8 * g4];
#pragma unroll
        for (int g = 0; g < 4; ++g)
          accX[g] = __builtin_amdgcn_mfma_f32_16x16x32_bf16(
              a0[g], fx0, (float4v){0.f, 0.f, 0.f, 0.f}, 0, 0, 0);
      }

      // ---- 8 h-MFMAs, 2-deep: acc = a2*fh1 + (a1*fh0 + accX) ----
      float4v acc[4];
#pragma unroll
      for (int g = 0; g < 4; ++g)
        acc[g] = __builtin_amdgcn_mfma_f32_16x16x32_bf16(a1[g], fh0, accX[g], 0, 0, 0);
#pragma unroll
      for (int g = 0; g < 4; ++g)
        acc[g] = __builtin_amdgcn_mfma_f32_16x16x32_bf16(a2[g], fh1, acc[g], 0, 0, 0);

      // ---- seed accX for t+1 (x_lds stable all chunk); executes under act --
      if (tt < TS - 1) {
        const short8v nfx = *(const short8v*)&x_lds[xb][tt + 1][row][8 * g4];
#pragma unroll
        for (int g = 0; g < 4; ++g)
          accX[g] = __builtin_amdgcn_mfma_f32_16x16x32_bf16(
              a0[g], nfx, (float4v){0.f, 0.f, 0.f, 0.f}, 0, 0, 0);
      }

      // ---- pick this thread's element (reg-select tree) and activate ----
      float gsel[4];
#pragma unroll
      for (int g = 0; g < 4; ++g) {
        const float x01 = sel1 ? acc[g][1] : acc[g][0];
        const float x23 = sel1 ? acc[g][3] : acc[g][2];
        gsel[g] = sel2 ? x23 : x01;
      }
      const float iv = fsig(gsel[0]);
      const float fv = fsig(gsel[1]);
      const float gv = ftanh(gsel[2]);
      const float ov = fsig(gsel[3]);
      c = fv * c + iv * gv;
      const float h = ov * ftanh(c);
      h_lds[hb ^ 1][row][jh] = cvt_bf16(h);
      if (t == T_LEN - 1) hf[row][jh] = h;
      if (tt == TS - 1 && more) stage_write((ch + 1) & 1);
      __syncthreads();  // one barrier per step
    }
  }

  // ---- epilogue: out[b] = sigmoid(hT . fc_w + fc_b) ----
  if (tid < R) {
    float a = fc_b[0];
#pragma unroll
    for (int k = 0; k < 64; ++k) a += hf[tid][k] * fc_w[k];
    out[bBase + tid] = fsig(a);
  }
}
}  // namespace

extern "C" void kernel_launch(void* const* d_in, const int* in_sizes, int n_in,
                              void* d_out, int out_size, void* d_ws,
                              size_t ws_size, hipStream_t stream) {
  const float* x    = (const float*)d_in[0];
  const float* W_ih = (const float*)d_in[1];
  const float* W_hh = (const float*)d_in[2];
  const float* b_ih = (const float*)d_in[3];
  const float* b_hh = (const float*)d_in[4];
  const float* fc_w = (const float*)d_in[5];
  const float* fc_b = (const float*)d_in[6];
  float* out = (float*)d_out;

  const int B = in_sizes[0] / (T_LEN * 8);  // 2048
  lstm_split<<<dim3(B / R), dim3(256), 0, stream>>>(x, W_ih, W_hh, b_ih, b_hh,
                                                    fc_w, fc_b, out);
}

// Round 10
// 451.516 us; speedup vs baseline: 1.0696x; 1.0696x over previous
//
#include <hip/hip_runtime.h>

// LSTM (B=2048, T=1024, I=8, H=64) + sigmoid(FC), bf16 MFMA, in-register
// activations, duplicate-column split, 2 blocks/CU — ANTI-PHASE + FX-PREFETCH.
//
// r8 (393us, WIN): one-time ~384cy s_sleep stagger for half the blocks seeds
// MFMA/VALU anti-phase between the 2 co-resident blocks (verified:
// MfmaUtil 48 + VALUBusy 64.5 = 112.5% > 100%). DO NOT REMOVE THE STAGGER.
// r9 (462us, FAIL): moving the x-MFMAs mid-step broke the lock (sum -> 90%).
// Lesson: do not reorder/split the 12-MFMA block or carry acc state across
// the barrier.
//
// r10 (this revision) = r8 + fx REGISTER PREFETCH only: the next step's fx
// fragment (x_lds[xb][tt+1], stable all chunk) is ds_read into a register
// during the act phase (pre-barrier), where its ~120cy latency is free.
// Post-barrier the wave issues only fh0/fh1 reads; the 4 x-MFMAs (operands
// in regs) issue immediately and their pipe time covers the fh latency.
// MFMA order (x -> h0 -> h1, 12 consecutive) is byte-identical to r8.
// Chunk boundary (tt==0, x buffer just restaged) reads post-barrier —
// compile-time branch under the full unroll, 1/32 steps.
//
// Verified keeps: HP=80 (r0's 40 aliased h rows — correctness), __expf
// (r2: exp2f lowers to slow ocml, +22% VALU), v_cvt_pk_bf16_f32 h-store,
// plain __syncthreads (r1 asm barriers regressed), full unroll on tt.

namespace {
constexpr int T_LEN = 1024;
constexpr int R     = 4;    // batch rows per block
constexpr int TS    = 32;   // timesteps of x per staged chunk
constexpr int HP    = 80;   // h_lds row stride in shorts (160 B, 16B-aligned)

typedef __attribute__((ext_vector_type(8))) short  short8v;
typedef __attribute__((ext_vector_type(4))) float  float4v;
typedef unsigned short u16;
typedef unsigned long long u64;
typedef unsigned int u32;

__device__ __forceinline__ float fsig(float x) {
  return __builtin_amdgcn_rcpf(1.f + __expf(-x));
}
__device__ __forceinline__ float ftanh(float x) {
  return 1.f - 2.f * __builtin_amdgcn_rcpf(__expf(2.f * x) + 1.f);
}
__device__ __forceinline__ u16 f2bf(float f) {  // RNE (init-time only)
  u32 u = __float_as_uint(f);
  u32 r = ((u >> 16) & 1u) + 0x7fffu;
  return (u16)((u + r) >> 16);
}
__device__ __forceinline__ u16 cvt_bf16(float f) {  // 1 VALU op, RNE
  u32 d;
  asm("v_cvt_pk_bf16_f32 %0, %1, %2" : "=v"(d) : "v"(f), "v"(f));
  return (u16)d;
}

__global__ __launch_bounds__(256, 2) void lstm_split(
    const float* __restrict__ x,     // [B, T, 8]
    const float* __restrict__ W_ih,  // [256, 8]
    const float* __restrict__ W_hh,  // [256, 64]
    const float* __restrict__ b_ih,  // [256]
    const float* __restrict__ b_hh,  // [256]
    const float* __restrict__ fc_w,  // [64]
    const float* __restrict__ fc_b,  // [1]
    float* __restrict__ out) {       // [B]
  __shared__ __align__(16) u16   x_lds[2][TS][R][32];  // 16 KB; full K-rows
  __shared__ __align__(16) u16   h_lds[2][R][HP];      // 2.5 KB
  __shared__ __align__(16) float hf[R][64];            // final h (fp32)

  const int tid  = threadIdx.x;
  const int lane = tid & 63;
  const int wv   = tid >> 6;       // wave 0..3
  const int g4   = lane >> 4;      // MFMA k-quad / C row-quad
  const int nib  = lane & 15;      // MFMA m/n coord
  const int row  = nib & 3;        // batch row (cols 4..15 duplicate 0..3)
  const int rsel = nib >> 2;       // which acc reg this thread activates
  const int jh   = 16 * wv + 4 * g4 + rsel;  // owned h index
  const int bBase = blockIdx.x * R;

  // ---- static A fragments: wave wv holds tiles {4g+wv}, g=0..3 (i,f,g,o) ----
  // A[m=16*(4g+wv)+nib][k=8*g4+j]; frag0 k=0..31 = [W_ih(8)|bias|0...],
  // frag1 = W_hh[:,0:32], frag2 = W_hh[:,32:64].
  short8v a0[4], a1[4], a2[4];
  for (int g = 0; g < 4; ++g) {
    const int n = 64 * g + 16 * wv + nib;  // gate row
    short8v f0, f1, f2;
    for (int j = 0; j < 8; ++j) {
      const int k = 8 * g4 + j;
      float v0 = 0.f;
      if (k < 8) v0 = W_ih[n * 8 + k];
      else if (k == 8) v0 = b_ih[n] + b_hh[n];
      f0[j] = (short)f2bf(v0);
      f1[j] = (short)f2bf(W_hh[n * 64 + k]);
      f2[j] = (short)f2bf(W_hh[n * 64 + 32 + k]);
    }
    a0[g] = f0; a1[g] = f1; a2[g] = f2;
  }

  // ---- LDS init: h0 = 0 (both bufs); x constant channels once per buf ----
  for (int i = tid; i < 2 * R * HP; i += 256) ((u16*)h_lds)[i] = 0;
  {  // 256 threads <-> 2 bufs x 32 tt x 4 rows
    const int buf = tid >> 7, rem = tid & 127, tt = rem >> 2, rr = rem & 3;
    u16* p = &x_lds[buf][tt][rr][0];
    p[8] = 0x3f80;  // bias channel = 1.0
    for (int chn = 9; chn < 32; ++chn) p[chn] = 0;
  }

  // ---- x staging: 1 float4/thread/chunk, double-buffered ----
  float4v xr;
  const int sr = tid >> 6, sm = tid & 63;          // src row, float4 idx
  const int stt = sm >> 1, sch = (sm & 1) * 4;     // dest tt, channel
  auto stage_load = [&](int chunk) {
    const float* src = x + ((size_t)bBase + sr) * (T_LEN * 8) +
                       (size_t)chunk * (TS * 8);
    xr = *(const float4v*)&src[sm * 4];
  };
  auto stage_write = [&](int buf) {
    u32 lo, hi;
    asm("v_cvt_pk_bf16_f32 %0, %1, %2" : "=v"(lo) : "v"(xr[0]), "v"(xr[1]));
    asm("v_cvt_pk_bf16_f32 %0, %1, %2" : "=v"(hi) : "v"(xr[2]), "v"(xr[3]));
    const u64 p = ((u64)hi << 32) | (u64)lo;
    *(u64*)&x_lds[buf][stt][sr][sch] = p;
  };

  stage_load(0);
  stage_write(0);
  __syncthreads();

  // ---- ANTI-PHASE SEED: one-time ~384cy stagger for half the blocks ----
  // Splits co-resident pairs whether the CU pairing is (i, i+256) (XCD
  // round-robin, differs in bit 8) or (2i, 2i+1) (differs in bit 0).
  if (((blockIdx.x ^ (blockIdx.x >> 8)) & 1) != 0)
    __builtin_amdgcn_s_sleep(6);  // 6*64 = 384 cycles, once

  // hoisted select masks for the cndmask tree
  const bool sel1 = (rsel & 1) != 0;
  const bool sel2 = (rsel & 2) != 0;
  float c = 0.f;

  short8v fxr;  // x B-fragment, prefetched one step ahead (pre-barrier)

  for (int ch = 0; ch < T_LEN / TS; ++ch) {
    const int xb = ch & 1;
    const bool more = (ch < T_LEN / TS - 1);
#pragma unroll
    for (int tt = 0; tt < TS; ++tt) {
      const int t = ch * TS + tt;
      const int hb = t & 1;  // == tt & 1 (TS even); compile-time under unroll
      if (tt == 0 && more) stage_load(ch + 1);  // reg loads; drain in stage_write

      // ---- chunk boundary: x buffer was restaged, read fx post-barrier ----
      if (tt == 0) fxr = *(const short8v*)&x_lds[xb][0][row][8 * g4];

      // ---- post-barrier head: only h fragments (2 uniform b128 reads) ----
      const short8v fh0 = *(const short8v*)&h_lds[hb][row][8 * g4];
      const short8v fh1 = *(const short8v*)&h_lds[hb][row][32 + 8 * g4];

      // ---- 12 MFMAs, r8-identical order: x (regs, no wait) -> h0 -> h1 ----
      float4v acc[4];
#pragma unroll
      for (int g = 0; g < 4; ++g)
        acc[g] = __builtin_amdgcn_mfma_f32_16x16x32_bf16(
            a0[g], fxr, (float4v){0.f, 0.f, 0.f, 0.f}, 0, 0, 0);
#pragma unroll
      for (int g = 0; g < 4; ++g)
        acc[g] = __builtin_amdgcn_mfma_f32_16x16x32_bf16(a1[g], fh0, acc[g], 0, 0, 0);
#pragma unroll
      for (int g = 0; g < 4; ++g)
        acc[g] = __builtin_amdgcn_mfma_f32_16x16x32_bf16(a2[g], fh1, acc[g], 0, 0, 0);

      // ---- pick this thread's element (reg-select tree) ----
      float gsel[4];
#pragma unroll
      for (int g = 0; g < 4; ++g) {
        const float x01 = sel1 ? acc[g][1] : acc[g][0];
        const float x23 = sel1 ? acc[g][3] : acc[g][2];
        gsel[g] = sel2 ? x23 : x01;
      }

      // ---- prefetch next step's fx during the act phase (latency free) ----
      if (tt < TS - 1) fxr = *(const short8v*)&x_lds[xb][tt + 1][row][8 * g4];

      // ---- activate ----
      const float iv = fsig(gsel[0]);
      const float fv = fsig(gsel[1]);
      const float gv = ftanh(gsel[2]);
      const float ov = fsig(gsel[3]);
      c = fv * c + iv * gv;
      const float h = ov * ftanh(c);
      h_lds[hb ^ 1][row][jh] = cvt_bf16(h);
      if (t == T_LEN - 1) hf[row][jh] = h;
      if (tt == TS - 1 && more) stage_write((ch + 1) & 1);
      __syncthreads();  // one barrier per step
    }
  }

  // ---- epilogue: out[b] = sigmoid(hT . fc_w + fc_b) ----
  if (tid < R) {
    float a = fc_b[0];
#pragma unroll
    for (int k = 0; k < 64; ++k) a += hf[tid][k] * fc_w[k];
    out[bBase + tid] = fsig(a);
  }
}
}  // namespace

extern "C" void kernel_launch(void* const* d_in, const int* in_sizes, int n_in,
                              void* d_out, int out_size, void* d_ws,
                              size_t ws_size, hipStream_t stream) {
  const float* x    = (const float*)d_in[0];
  const float* W_ih = (const float*)d_in[1];
  const float* W_hh = (const float*)d_in[2];
  const float* b_ih = (const float*)d_in[3];
  const float* b_hh = (const float*)d_in[4];
  const float* fc_w = (const float*)d_in[5];
  const float* fc_b = (const float*)d_in[6];
  float* out = (float*)d_out;

  const int B = in_sizes[0] / (T_LEN * 8);  // 2048
  lstm_split<<<dim3(B / R), dim3(256), 0, stream>>>(x, W_ih, W_hh, b_ih, b_hh,
                                                    fc_w, fc_b, out);
}

// Round 11
// 420.997 us; speedup vs baseline: 1.1472x; 1.0725x over previous
//
#include <hip/hip_runtime.h>

// LSTM (B=2048, T=1024, I=8, H=64) + sigmoid(FC), bf16 MFMA, in-register
// activations, duplicate-column split, 2 blocks/CU — ANTI-PHASE revision,
// stagger tuned to half the step period.
//
// Machine model (locked r0-r10): per step the two co-resident blocks each
// run an MFMA phase (~440cy pipe) then a VALU act phase (~480cy). Unstaggered
// they phase-lock (both pipes serialize: 1116cy wall). A ONE-TIME s_sleep
// stagger for half the blocks seeds anti-phase — MFMA of one block overlaps
// VALU of the other — and the equilibrium self-sustains (contention repels
// same-phase drift). Verified r8: 393us, MfmaUtil+VALUBusy = 112.5% > 100%.
//
// THE LOCK IS FRAGILE TO ANY LOOP-BODY EDIT (measured):
//   r9  (x-MFMAs moved mid-step, acc across barrier): sum 90%, 462us.
//   r10 (fx ds_read hoisted into act phase):          sum 99%, 425us.
// => loop body below is byte-identical to r8. DO NOT REORDER the 12-MFMA
// block, DO NOT move ds_reads across phases, DO NOT touch the barrier.
//
// r11: only change = s_sleep(6)->s_sleep(7) (384->448cy). r8's step wall is
// 923cy; ideal anti-phase seed is half the period ~460cy; 448 is closer
// than 384. Single-variable tune of the one knob outside the loop.
//
// Verified keeps: HP=80 (r0's 40 aliased h rows — correctness; bank
// conflicts 1.88e7->2.0e6), __expf (r2: exp2f lowers to slow ocml, +22%
// VALU), v_cvt_pk_bf16_f32 h-store (1 op, RNE), plain __syncthreads
// (r1 asm barriers regressed), full unroll on tt.

namespace {
constexpr int T_LEN = 1024;
constexpr int R     = 4;    // batch rows per block
constexpr int TS    = 32;   // timesteps of x per staged chunk
constexpr int HP    = 80;   // h_lds row stride in shorts (160 B, 16B-aligned)

typedef __attribute__((ext_vector_type(8))) short  short8v;
typedef __attribute__((ext_vector_type(4))) float  float4v;
typedef unsigned short u16;
typedef unsigned long long u64;
typedef unsigned int u32;

__device__ __forceinline__ float fsig(float x) {
  return __builtin_amdgcn_rcpf(1.f + __expf(-x));
}
__device__ __forceinline__ float ftanh(float x) {
  return 1.f - 2.f * __builtin_amdgcn_rcpf(__expf(2.f * x) + 1.f);
}
__device__ __forceinline__ u16 f2bf(float f) {  // RNE (init-time only)
  u32 u = __float_as_uint(f);
  u32 r = ((u >> 16) & 1u) + 0x7fffu;
  return (u16)((u + r) >> 16);
}
__device__ __forceinline__ u16 cvt_bf16(float f) {  // 1 VALU op, RNE
  u32 d;
  asm("v_cvt_pk_bf16_f32 %0, %1, %2" : "=v"(d) : "v"(f), "v"(f));
  return (u16)d;
}

__global__ __launch_bounds__(256, 2) void lstm_split(
    const float* __restrict__ x,     // [B, T, 8]
    const float* __restrict__ W_ih,  // [256, 8]
    const float* __restrict__ W_hh,  // [256, 64]
    const float* __restrict__ b_ih,  // [256]
    const float* __restrict__ b_hh,  // [256]
    const float* __restrict__ fc_w,  // [64]
    const float* __restrict__ fc_b,  // [1]
    float* __restrict__ out) {       // [B]
  __shared__ __align__(16) u16   x_lds[2][TS][R][32];  // 16 KB; full K-rows
  __shared__ __align__(16) u16   h_lds[2][R][HP];      // 2.5 KB
  __shared__ __align__(16) float hf[R][64];            // final h (fp32)

  const int tid  = threadIdx.x;
  const int lane = tid & 63;
  const int wv   = tid >> 6;       // wave 0..3
  const int g4   = lane >> 4;      // MFMA k-quad / C row-quad
  const int nib  = lane & 15;      // MFMA m/n coord
  const int row  = nib & 3;        // batch row (cols 4..15 duplicate 0..3)
  const int rsel = nib >> 2;       // which acc reg this thread activates
  const int jh   = 16 * wv + 4 * g4 + rsel;  // owned h index
  const int bBase = blockIdx.x * R;

  // ---- static A fragments: wave wv holds tiles {4g+wv}, g=0..3 (i,f,g,o) ----
  // A[m=16*(4g+wv)+nib][k=8*g4+j]; frag0 k=0..31 = [W_ih(8)|bias|0...],
  // frag1 = W_hh[:,0:32], frag2 = W_hh[:,32:64].
  short8v a0[4], a1[4], a2[4];
  for (int g = 0; g < 4; ++g) {
    const int n = 64 * g + 16 * wv + nib;  // gate row
    short8v f0, f1, f2;
    for (int j = 0; j < 8; ++j) {
      const int k = 8 * g4 + j;
      float v0 = 0.f;
      if (k < 8) v0 = W_ih[n * 8 + k];
      else if (k == 8) v0 = b_ih[n] + b_hh[n];
      f0[j] = (short)f2bf(v0);
      f1[j] = (short)f2bf(W_hh[n * 64 + k]);
      f2[j] = (short)f2bf(W_hh[n * 64 + 32 + k]);
    }
    a0[g] = f0; a1[g] = f1; a2[g] = f2;
  }

  // ---- LDS init: h0 = 0 (both bufs); x constant channels once per buf ----
  for (int i = tid; i < 2 * R * HP; i += 256) ((u16*)h_lds)[i] = 0;
  {  // 256 threads <-> 2 bufs x 32 tt x 4 rows
    const int buf = tid >> 7, rem = tid & 127, tt = rem >> 2, rr = rem & 3;
    u16* p = &x_lds[buf][tt][rr][0];
    p[8] = 0x3f80;  // bias channel = 1.0
    for (int chn = 9; chn < 32; ++chn) p[chn] = 0;
  }

  // ---- x staging: 1 float4/thread/chunk, double-buffered ----
  float4v xr;
  const int sr = tid >> 6, sm = tid & 63;          // src row, float4 idx
  const int stt = sm >> 1, sch = (sm & 1) * 4;     // dest tt, channel
  auto stage_load = [&](int chunk) {
    const float* src = x + ((size_t)bBase + sr) * (T_LEN * 8) +
                       (size_t)chunk * (TS * 8);
    xr = *(const float4v*)&src[sm * 4];
  };
  auto stage_write = [&](int buf) {
    u32 lo, hi;
    asm("v_cvt_pk_bf16_f32 %0, %1, %2" : "=v"(lo) : "v"(xr[0]), "v"(xr[1]));
    asm("v_cvt_pk_bf16_f32 %0, %1, %2" : "=v"(hi) : "v"(xr[2]), "v"(xr[3]));
    const u64 p = ((u64)hi << 32) | (u64)lo;
    *(u64*)&x_lds[buf][stt][sr][sch] = p;
  };

  stage_load(0);
  stage_write(0);
  __syncthreads();

  // ---- ANTI-PHASE SEED: one-time ~448cy stagger for half the blocks ----
  // Half the 923cy step period (~460cy) is the ideal offset; s_sleep(7) =
  // 448cy. Parity (blockIdx ^ blockIdx>>8)&1 splits co-resident pairs under
  // both plausible mappings: (i, i+256) XCD round-robin and (2i, 2i+1).
  if (((blockIdx.x ^ (blockIdx.x >> 8)) & 1) != 0)
    __builtin_amdgcn_s_sleep(7);  // 7*64 = 448 cycles, once

  // hoisted select masks for the cndmask tree
  const bool sel1 = (rsel & 1) != 0;
  const bool sel2 = (rsel & 2) != 0;
  float c = 0.f;

  for (int ch = 0; ch < T_LEN / TS; ++ch) {
    const int xb = ch & 1;
    const bool more = (ch < T_LEN / TS - 1);
#pragma unroll
    for (int tt = 0; tt < TS; ++tt) {
      const int t = ch * TS + tt;
      const int hb = t & 1;  // == tt & 1 (TS even); compile-time under unroll
      if (tt == 0 && more) stage_load(ch + 1);  // reg loads; drain in stage_write

      // ---- B fragments (uniform b128 reads) ----
      const short8v fx  = *(const short8v*)&x_lds[xb][tt][row][8 * g4];
      const short8v fh0 = *(const short8v*)&h_lds[hb][row][8 * g4];
      const short8v fh1 = *(const short8v*)&h_lds[hb][row][32 + 8 * g4];

      // ---- 12 MFMAs: 4 gate-quads x (x | h-lo | h-hi) ----
      float4v acc[4];
#pragma unroll
      for (int g = 0; g < 4; ++g)
        acc[g] = __builtin_amdgcn_mfma_f32_16x16x32_bf16(
            a0[g], fx, (float4v){0.f, 0.f, 0.f, 0.f}, 0, 0, 0);
#pragma unroll
      for (int g = 0; g < 4; ++g)
        acc[g] = __builtin_amdgcn_mfma_f32_16x16x32_bf16(a1[g], fh0, acc[g], 0, 0, 0);
#pragma unroll
      for (int g = 0; g < 4; ++g)
        acc[g] = __builtin_amdgcn_mfma_f32_16x16x32_bf16(a2[g], fh1, acc[g], 0, 0, 0);

      // ---- pick this thread's element (reg-select tree) and activate ----
      float gsel[4];
#pragma unroll
      for (int g = 0; g < 4; ++g) {
        const float x01 = sel1 ? acc[g][1] : acc[g][0];
        const float x23 = sel1 ? acc[g][3] : acc[g][2];
        gsel[g] = sel2 ? x23 : x01;
      }
      const float iv = fsig(gsel[0]);
      const float fv = fsig(gsel[1]);
      const float gv = ftanh(gsel[2]);
      const float ov = fsig(gsel[3]);
      c = fv * c + iv * gv;
      const float h = ov * ftanh(c);
      h_lds[hb ^ 1][row][jh] = cvt_bf16(h);
      if (t == T_LEN - 1) hf[row][jh] = h;
      if (tt == TS - 1 && more) stage_write((ch + 1) & 1);
      __syncthreads();  // one barrier per step
    }
  }

  // ---- epilogue: out[b] = sigmoid(hT . fc_w + fc_b) ----
  if (tid < R) {
    float a = fc_b[0];
#pragma unroll
    for (int k = 0; k < 64; ++k) a += hf[tid][k] * fc_w[k];
    out[bBase + tid] = fsig(a);
  }
}
}  // namespace

extern "C" void kernel_launch(void* const* d_in, const int* in_sizes, int n_in,
                              void* d_out, int out_size, void* d_ws,
                              size_t ws_size, hipStream_t stream) {
  const float* x    = (const float*)d_in[0];
  const float* W_ih = (const float*)d_in[1];
  const float* W_hh = (const float*)d_in[2];
  const float* b_ih = (const float*)d_in[3];
  const float* b_hh = (const float*)d_in[4];
  const float* fc_w = (const float*)d_in[5];
  const float* fc_b = (const float*)d_in[6];
  float* out = (float*)d_out;

  const int B = in_sizes[0] / (T_LEN * 8);  // 2048
  lstm_split<<<dim3(B / R), dim3(256), 0, stream>>>(x, W_ih, W_hh, b_ih, b_hh,
                                                    fc_w, fc_b, out);
}